// Round 14
// baseline (329.435 us; speedup 1.0000x reference)
//
#include <hip/hip_runtime.h>
#include <hip/hip_fp16.h>

#define Bb   2
#define Cc   256
#define Hh   256
#define Ww   256
#define Nn   100000
#define HWp  65536
#define TOK2 128
#define NB2  ((Nn + TOK2 - 1) / TOK2)   // 782
#define BUCK 16                          // Poisson-safe (lambda=1.53, P(overflow)~1e-8)

typedef float    f32x4 __attribute__((ext_vector_type(4)));
typedef unsigned u32x4 __attribute__((ext_vector_type(4)));

__device__ __forceinline__ float4 nt_load_f4(const float* p) {
    f32x4 v = __builtin_nontemporal_load((const f32x4*)p);
    return make_float4(v.x, v.y, v.z, v.w);
}
__device__ __forceinline__ void nt_store_f4(const float4& v, float* p) {
    f32x4 e; e.x = v.x; e.y = v.y; e.z = v.z; e.w = v.w;
    __builtin_nontemporal_store(e, (f32x4*)p);
}

// ---------------- Kernel 0: zero the cell counters ------------
__global__ __launch_bounds__(256) void zero_cnt_kernel(uint4* __restrict__ p)
{
    p[blockIdx.x * 256 + threadIdx.x] = make_uint4(0u, 0u, 0u, 0u);
}

// ---------------- Kernel 1: single-pass transpose (raw f16) + stats + bucket fill --------
// v14: stores interleaved into the k-loop (one 16B slot per token as soon as complete)
// -> no persistent out[4][4] array -> lower VGPR -> higher occupancy.
__global__ __launch_bounds__(256) void ln_bucket_kernel(
    const float* __restrict__ tokens, const int* __restrict__ fidx,
    __half* __restrict__ ln_raw, float2* __restrict__ mustats,
    int* __restrict__ cntInt, int* __restrict__ bucket)
{
    __shared__ float ps [8][TOK2 + 4];
    __shared__ float pss[8][TOK2 + 4];

    const int tid = threadIdx.x;
    const int bt  = blockIdx.x;
    const int b   = bt / NB2;
    const int n0  = (bt % NB2) * TOK2;
    const int tq  = tid & 31;        // token quad: tokens t0..t0+3
    const int cg  = tid >> 5;        // channel group: channels c0..c0+31
    const int t0  = tq * 4;
    const int c0  = cg * 32;
    const int nvalid = min(TOK2, Nn - n0);   // 128 or 32 -> always %4==0

    const float* tcol = tokens + (size_t)b * Cc * Nn + n0 + t0;

    float s0=0,s1=0,s2=0,s3=0, q0=0,q1=0,q2=0,q3=0;

    if (t0 < nvalid) {
        uint4* row0 = (uint4*)(ln_raw + ((size_t)b * Nn + n0 + t0 + 0) * Cc + c0);
        uint4* row1 = (uint4*)(ln_raw + ((size_t)b * Nn + n0 + t0 + 1) * Cc + c0);
        uint4* row2 = (uint4*)(ln_raw + ((size_t)b * Nn + n0 + t0 + 2) * Cc + c0);
        uint4* row3 = (uint4*)(ln_raw + ((size_t)b * Nn + n0 + t0 + 3) * Cc + c0);
        uint4 cur0, cur1, cur2, cur3;

        #pragma unroll
        for (int k = 0; k < 8; ++k) {
            const int cb = c0 + 4 * k;
            float4 v0 = nt_load_f4(&tcol[(size_t)(cb + 0) * Nn]);
            float4 v1 = nt_load_f4(&tcol[(size_t)(cb + 1) * Nn]);
            float4 v2 = nt_load_f4(&tcol[(size_t)(cb + 2) * Nn]);
            float4 v3 = nt_load_f4(&tcol[(size_t)(cb + 3) * Nn]);

            s0 += v0.x + v1.x + v2.x + v3.x;
            q0 += v0.x*v0.x + v1.x*v1.x + v2.x*v2.x + v3.x*v3.x;
            s1 += v0.y + v1.y + v2.y + v3.y;
            q1 += v0.y*v0.y + v1.y*v1.y + v2.y*v2.y + v3.y*v3.y;
            s2 += v0.z + v1.z + v2.z + v3.z;
            q2 += v0.z*v0.z + v1.z*v1.z + v2.z*v2.z + v3.z*v3.z;
            s3 += v0.w + v1.w + v2.w + v3.w;
            q3 += v0.w*v0.w + v1.w*v1.w + v2.w*v2.w + v3.w*v3.w;

            __half2 h;
            unsigned p00, p01, p10, p11, p20, p21, p30, p31;
            h = __floats2half2_rn(v0.x, v1.x); p00 = *(unsigned*)&h;
            h = __floats2half2_rn(v2.x, v3.x); p01 = *(unsigned*)&h;
            h = __floats2half2_rn(v0.y, v1.y); p10 = *(unsigned*)&h;
            h = __floats2half2_rn(v2.y, v3.y); p11 = *(unsigned*)&h;
            h = __floats2half2_rn(v0.z, v1.z); p20 = *(unsigned*)&h;
            h = __floats2half2_rn(v2.z, v3.z); p21 = *(unsigned*)&h;
            h = __floats2half2_rn(v0.w, v1.w); p30 = *(unsigned*)&h;
            h = __floats2half2_rn(v2.w, v3.w); p31 = *(unsigned*)&h;

            if ((k & 1) == 0) {
                cur0.x = p00; cur0.y = p01;
                cur1.x = p10; cur1.y = p11;
                cur2.x = p20; cur2.y = p21;
                cur3.x = p30; cur3.y = p31;
            } else {
                const int m = k >> 1;
                cur0.z = p00; cur0.w = p01; row0[m] = cur0;
                cur1.z = p10; cur1.w = p11; row1[m] = cur1;
                cur2.z = p20; cur2.w = p21; row2[m] = cur2;
                cur3.z = p30; cur3.w = p31; row3[m] = cur3;
            }
        }
        ps [cg][t0+0] = s0; ps [cg][t0+1] = s1; ps [cg][t0+2] = s2; ps [cg][t0+3] = s3;
        pss[cg][t0+0] = q0; pss[cg][t0+1] = q1; pss[cg][t0+2] = q2; pss[cg][t0+3] = q3;
    }

    if (tid < nvalid) {
        int bin  = fidx[b * Nn + n0 + tid];
        int cell = b * HWp + bin;
        int slot = atomicAdd(&cntInt[cell], 1);
        if (slot < BUCK) bucket[(size_t)cell * BUCK + slot] = n0 + tid;
    }
    __syncthreads();

    if (tid < nvalid) {
        float sum = 0.f, ssq = 0.f;
        #pragma unroll
        for (int k = 0; k < 8; ++k) { sum += ps[k][tid]; ssq += pss[k][tid]; }
        float mu  = sum * (1.0f / Cc);
        float var = ssq * (1.0f / Cc) - mu * mu;
        mustats[(size_t)b * Nn + n0 + tid] = make_float2(mu, rsqrtf(var + 1e-5f));
    }
}

// ---------------- Kernel 2: per-cell mean + deferred LayerNorm (wave per cell) ----------
__global__ __launch_bounds__(256) void cell_mean_kernel(
    const __half* __restrict__ ln_raw, const float2* __restrict__ mustats,
    const int* __restrict__ cntInt, const int* __restrict__ bucket,
    const float* __restrict__ lnw, const float* __restrict__ lnb,
    __half* __restrict__ grid)
{
    const int wave = (int)((blockIdx.x * 256 + threadIdx.x) >> 6);  // cell index (b*HW+hw)
    const int lane = threadIdx.x & 63;
    const int b    = wave >> 16;

    int cnt = min(cntInt[wave], BUCK);
    float a0 = 0.f, a1 = 0.f, a2 = 0.f, a3 = 0.f;
    for (int t = 0; t < cnt; ++t) {
        int tok = bucket[(size_t)wave * BUCK + t];
        float2 ms = mustats[(size_t)b * Nn + tok];          // wave-uniform broadcast
        uint2 v = ((const uint2*)(ln_raw + ((size_t)b * Nn + tok) * Cc))[lane];
        __half2 p0 = *(__half2*)&v.x, p1 = *(__half2*)&v.y;
        float2 f0 = __half22float2(p0), f1 = __half22float2(p1);
        a0 += (f0.x - ms.x) * ms.y;
        a1 += (f0.y - ms.x) * ms.y;
        a2 += (f1.x - ms.x) * ms.y;
        a3 += (f1.y - ms.x) * ms.y;
    }
    uint2 o;
    if (cnt > 0) {
        const float inv = 1.0f / (float)cnt;
        float4 w4 = *(const float4*)&lnw[lane * 4];
        float4 b4 = *(const float4*)&lnb[lane * 4];
        __half2 o0 = __floats2half2_rn(w4.x * (a0 * inv) + b4.x, w4.y * (a1 * inv) + b4.y);
        __half2 o1 = __floats2half2_rn(w4.z * (a2 * inv) + b4.z, w4.w * (a3 * inv) + b4.w);
        o.x = *(unsigned*)&o0; o.y = *(unsigned*)&o1;
    } else {
        o.x = 0u; o.y = 0u;
    }
    ((uint2*)(grid + (size_t)wave * Cc))[lane] = o;
}

// ---------------- Kernel 3: FUSED depthwise 3x3 -> ReLU -> 3x3 -> scale ----------------
__global__ __launch_bounds__(256, 3) void dwconv_fused_kernel(
    const __half* __restrict__ in, const float* __restrict__ w1, const float* __restrict__ b1,
    const float* __restrict__ w2, const float* __restrict__ b2,
    const float* __restrict__ sw, __half* __restrict__ out)
{
    __shared__ uint4 in_s [10 * 20 * 8];   // 25.6 KB
    __shared__ uint4 mid_s[ 8 * 18 * 8];   // 18.4 KB

    const int tid = threadIdx.x;
    const int bid = blockIdx.x;
    const int rem = bid % 2752;            // 4 * 16 * 43
    const int bo  = bid / 2752;
    const int cgi = rem & 3;
    const int tx  = (rem >> 2) & 15;
    const int ty  = rem >> 6;              // 0..42
    const int c0  = cgi * 64;
    const int x0  = tx * 16;
    const int y0  = ty * 6;

    const int u   = tid & 7;
    const int pxl = tid >> 3;

    const __half* gin = in + (size_t)bo * HWp * Cc + c0;
    #pragma unroll
    for (int it = 0; it < 7; ++it) {
        int p = it * 32 + pxl;
        if (p < 200) {
            int r = p / 20, c = p - r * 20;
            int gh = y0 + r - 2, gw = x0 + c - 2;
            uint4 v = make_uint4(0, 0, 0, 0);
            if ((unsigned)gh < 256u && (unsigned)gw < 256u)
                v = *(const uint4*)(gin + ((size_t)(gh * 256 + gw)) * Cc + u * 8);
            in_s[p * 8 + u] = v;
        }
    }

    float wA[72], bA[8];
    {
        const float4* wp = (const float4*)(w1 + (size_t)(c0 + u * 8) * 9);
        #pragma unroll
        for (int i = 0; i < 18; ++i) ((float4*)wA)[i] = wp[i];
        const float4* bp = (const float4*)(b1 + c0 + u * 8);
        ((float4*)bA)[0] = bp[0]; ((float4*)bA)[1] = bp[1];
    }
    __syncthreads();

    #pragma unroll
    for (int it = 0; it < 5; ++it) {
        int p = it * 32 + pxl;             // valid < 144
        if (p < 144) {
            int r = p / 18, c = p - r * 18;
            const int gh = y0 + r - 1, gw = x0 + c - 1;
            const bool inimg = ((unsigned)gh < 256u) && ((unsigned)gw < 256u);
            float acc[8];
            #pragma unroll
            for (int j = 0; j < 8; ++j) acc[j] = bA[j];
            #pragma unroll
            for (int dr = 0; dr < 3; ++dr) {
                #pragma unroll
                for (int dc = 0; dc < 3; ++dc) {
                    uint4 v = in_s[((r + dr) * 20 + (c + dc)) * 8 + u];
                    const int k = dr * 3 + dc;
                    #pragma unroll
                    for (int e = 0; e < 4; ++e) {
                        float2 f = __half22float2(*(const __half2*)&((const unsigned*)&v)[e]);
                        acc[2*e]   += f.x * wA[(2*e)     * 9 + k];
                        acc[2*e+1] += f.y * wA[(2*e + 1) * 9 + k];
                    }
                }
            }
            uint4 o;
            if (inimg) {
                #pragma unroll
                for (int e = 0; e < 4; ++e) {
                    __half2 h = __floats2half2_rn(fmaxf(acc[2*e], 0.f), fmaxf(acc[2*e+1], 0.f));
                    ((unsigned*)&o)[e] = *(unsigned*)&h;
                }
            } else {
                o = make_uint4(0, 0, 0, 0);
            }
            mid_s[p * 8 + u] = o;
        }
    }

    float wB[72], bB[8], sB[8];
    {
        const float4* wp = (const float4*)(w2 + (size_t)(c0 + u * 8) * 9);
        #pragma unroll
        for (int i = 0; i < 18; ++i) ((float4*)wB)[i] = wp[i];
        const float4* bp = (const float4*)(b2 + c0 + u * 8);
        ((float4*)bB)[0] = bp[0]; ((float4*)bB)[1] = bp[1];
        const float4* sp = (const float4*)(sw + c0 + u * 8);
        ((float4*)sB)[0] = sp[0]; ((float4*)sB)[1] = sp[1];
    }
    __syncthreads();

    __half* gout = out + (size_t)bo * HWp * Cc + c0;
    #pragma unroll
    for (int it = 0; it < 3; ++it) {
        int p = it * 32 + pxl;             // 0..95
        int r = p >> 4, c = p & 15;
        const int gh = y0 + r, gw = x0 + c;
        if (gh < 256) {
            float acc[8];
            #pragma unroll
            for (int j = 0; j < 8; ++j) acc[j] = bB[j];
            #pragma unroll
            for (int dr = 0; dr < 3; ++dr) {
                #pragma unroll
                for (int dc = 0; dc < 3; ++dc) {
                    uint4 v = mid_s[((r + dr) * 18 + (c + dc)) * 8 + u];
                    const int k = dr * 3 + dc;
                    #pragma unroll
                    for (int e = 0; e < 4; ++e) {
                        float2 f = __half22float2(*(const __half2*)&((const unsigned*)&v)[e]);
                        acc[2*e]   += f.x * wB[(2*e)     * 9 + k];
                        acc[2*e+1] += f.y * wB[(2*e + 1) * 9 + k];
                    }
                }
            }
            uint4 o;
            #pragma unroll
            for (int e = 0; e < 4; ++e) {
                __half2 h = __floats2half2_rn(acc[2*e] * sB[2*e], acc[2*e+1] * sB[2*e+1]);
                ((unsigned*)&o)[e] = *(unsigned*)&h;
            }
            *(uint4*)(gout + ((size_t)(gh * 256 + gw)) * Cc + u * 8) = o;
        }
    }
}

// ---------------- Kernel 4: gather + residual, register transpose, forced-MLP ----------
// v14: sched_barrier(0) after the 16 gather loads pins them ABOVE the residual loop --
// R8 profile showed VGPR=36, i.e. the compiler had sunk the loads to their uses and
// destroyed the 16-deep MLP this structure was designed for.
__global__ __launch_bounds__(256, 4) void gather_add_kernel(
    const float* __restrict__ tokens, const int* __restrict__ iidx,
    const __half* __restrict__ gcell, float* __restrict__ out)
{
    const int tid = threadIdx.x;
    const int bt  = blockIdx.x;
    const int b   = bt / NB2;
    const int n0  = (bt % NB2) * TOK2;
    const int tq  = tid & 31;
    const int cg  = tid >> 5;
    const int t0  = tq * 4;
    const int c0  = cg * 32;
    const int nvalid = min(TOK2, Nn - n0);   // 128 or 32 -> %4==0

    if (t0 >= nvalid) return;

    const int4 ii = *(const int4*)&iidx[(size_t)b * Nn + n0 + t0];
    const uint4* gb = (const uint4*)(gcell + (size_t)b * HWp * Cc);  // 32 uint4 per cell

    uint4 g0[4], g1[4], g2[4], g3[4];
    const uint4* r0 = gb + (size_t)ii.x * 32 + 4 * cg;
    const uint4* r1 = gb + (size_t)ii.y * 32 + 4 * cg;
    const uint4* r2 = gb + (size_t)ii.z * 32 + 4 * cg;
    const uint4* r3 = gb + (size_t)ii.w * 32 + 4 * cg;
    #pragma unroll
    for (int m = 0; m < 4; ++m) g0[m] = r0[m];
    #pragma unroll
    for (int m = 0; m < 4; ++m) g1[m] = r1[m];
    #pragma unroll
    for (int m = 0; m < 4; ++m) g2[m] = r2[m];
    #pragma unroll
    for (int m = 0; m < 4; ++m) g3[m] = r3[m];
    __builtin_amdgcn_sched_barrier(0);   // keep all 16 loads issued before any use below

    const float* tb = tokens + (size_t)b * Cc * Nn + n0 + t0;
    float*       ob = out    + (size_t)b * Cc * Nn + n0 + t0;

    #pragma unroll
    for (int m = 0; m < 4; ++m) {
        #pragma unroll
        for (int d = 0; d < 4; ++d) {
            const unsigned u0 = ((const unsigned*)&g0[m])[d];
            const unsigned u1 = ((const unsigned*)&g1[m])[d];
            const unsigned u2 = ((const unsigned*)&g2[m])[d];
            const unsigned u3 = ((const unsigned*)&g3[m])[d];
            const float2 f0 = __half22float2(*(const __half2*)&u0);
            const float2 f1 = __half22float2(*(const __half2*)&u1);
            const float2 f2 = __half22float2(*(const __half2*)&u2);
            const float2 f3 = __half22float2(*(const __half2*)&u3);
            const int cA = c0 + m * 8 + d * 2;
            float4 va = nt_load_f4(&tb[(size_t)cA * Nn]);
            va.x += f0.x; va.y += f1.x; va.z += f2.x; va.w += f3.x;
            nt_store_f4(va, &ob[(size_t)cA * Nn]);
            float4 vb = nt_load_f4(&tb[(size_t)(cA + 1) * Nn]);
            vb.x += f0.y; vb.y += f1.y; vb.z += f2.y; vb.w += f3.y;
            nt_store_f4(vb, &ob[(size_t)(cA + 1) * Nn]);
        }
    }
}

extern "C" void kernel_launch(void* const* d_in, const int* in_sizes, int n_in,
                              void* d_out, int out_size, void* d_ws, size_t ws_size,
                              hipStream_t stream)
{
    const float* tokens      = (const float*)d_in[0];
    const int*   flatten_idx = (const int*)  d_in[1];
    const int*   inflate_idx = (const int*)  d_in[2];
    const float* lnw         = (const float*)d_in[3];
    const float* lnb         = (const float*)d_in[4];
    const float* w1          = (const float*)d_in[5];
    const float* b1          = (const float*)d_in[6];
    const float* w2          = (const float*)d_in[7];
    const float* b2          = (const float*)d_in[8];
    const float* sw          = (const float*)d_in[9];
    float*       out         = (float*)d_out;

    char* ws = (char*)d_ws;
    const size_t gridBytes = (size_t)Bb * HWp * Cc * sizeof(__half);   // 33.6 MB each
    const size_t lnBytes   = (size_t)Bb * Nn * Cc * sizeof(__half);    // 102.4 MB
    const size_t msBytes   = (size_t)Bb * Nn * sizeof(float2);         // 1.6 MB
    __half* grid    = (__half*)ws;
    __half* grid2   = (__half*)(ws + gridBytes);
    __half* ln_raw  = (__half*)(ws + 2 * gridBytes);
    float2* mustats = (float2*)(ws + 2 * gridBytes + lnBytes);
    int*    cntInt  = (int*)   (ws + 2 * gridBytes + lnBytes + msBytes);
    int*    bucket  = (int*)   (ws + 2 * gridBytes + lnBytes + msBytes + (size_t)Bb * HWp * sizeof(int));

    zero_cnt_kernel<<<(Bb * HWp * sizeof(int)) / (256 * 16), 256, 0, stream>>>((uint4*)cntInt);
    ln_bucket_kernel<<<Bb * NB2, 256, 0, stream>>>(tokens, flatten_idx,
                                                   ln_raw, mustats, cntInt, bucket);
    cell_mean_kernel<<<(Bb * HWp) / 4, 256, 0, stream>>>(ln_raw, mustats, cntInt, bucket,
                                                         lnw, lnb, grid);
    dwconv_fused_kernel<<<2 * 4 * 16 * 43, 256, 0, stream>>>(grid, w1, b1, w2, b2, sw, grid2);
    gather_add_kernel<<<Bb * NB2, 256, 0, stream>>>(tokens, inflate_idx, grid2, out);
}

// Round 15
// 315.293 us; speedup vs baseline: 1.0449x; 1.0449x over previous
//
#include <hip/hip_runtime.h>
#include <hip/hip_fp16.h>

#define Bb   2
#define Cc   256
#define Hh   256
#define Ww   256
#define Nn   100000
#define HWp  65536
#define TOK2 128
#define NB2  ((Nn + TOK2 - 1) / TOK2)   // 782
#define BUCK 16                          // Poisson-safe (lambda=1.53, P(overflow)~1e-8)

typedef float    f32x4 __attribute__((ext_vector_type(4)));
typedef unsigned u32x4 __attribute__((ext_vector_type(4)));

__device__ __forceinline__ float4 nt_load_f4(const float* p) {
    f32x4 v = __builtin_nontemporal_load((const f32x4*)p);
    return make_float4(v.x, v.y, v.z, v.w);
}
__device__ __forceinline__ void nt_store_f4(const float4& v, float* p) {
    f32x4 e; e.x = v.x; e.y = v.y; e.z = v.z; e.w = v.w;
    __builtin_nontemporal_store(e, (f32x4*)p);
}

// ---------------- Kernel 0: zero the cell counters ------------
__global__ __launch_bounds__(256) void zero_cnt_kernel(uint4* __restrict__ p)
{
    p[blockIdx.x * 256 + threadIdx.x] = make_uint4(0u, 0u, 0u, 0u);
}

// ---------------- Kernel 1: single-pass transpose (raw f16) + stats + bucket fill --------
// R12 champion form: bulk out[4][4] epilogue stores (regular, L2-merged).
__global__ __launch_bounds__(256) void ln_bucket_kernel(
    const float* __restrict__ tokens, const int* __restrict__ fidx,
    __half* __restrict__ ln_raw, float2* __restrict__ mustats,
    int* __restrict__ cntInt, int* __restrict__ bucket)
{
    __shared__ float ps [8][TOK2 + 4];
    __shared__ float pss[8][TOK2 + 4];

    const int tid = threadIdx.x;
    const int bt  = blockIdx.x;
    const int b   = bt / NB2;
    const int n0  = (bt % NB2) * TOK2;
    const int tq  = tid & 31;        // token quad: tokens t0..t0+3
    const int cg  = tid >> 5;        // channel group: channels c0..c0+31
    const int t0  = tq * 4;
    const int c0  = cg * 32;
    const int nvalid = min(TOK2, Nn - n0);   // 128 or 32 -> always %4==0

    const float* tcol = tokens + (size_t)b * Cc * Nn + n0 + t0;

    float s0=0,s1=0,s2=0,s3=0, q0=0,q1=0,q2=0,q3=0;
    uint4 out[4][4];                 // [token i][uint4 slot m] : channels c0+8m..c0+8m+7

    if (t0 < nvalid) {
        #pragma unroll
        for (int k = 0; k < 8; ++k) {
            const int cb = c0 + 4 * k;
            float4 v0 = nt_load_f4(&tcol[(size_t)(cb + 0) * Nn]);
            float4 v1 = nt_load_f4(&tcol[(size_t)(cb + 1) * Nn]);
            float4 v2 = nt_load_f4(&tcol[(size_t)(cb + 2) * Nn]);
            float4 v3 = nt_load_f4(&tcol[(size_t)(cb + 3) * Nn]);

            s0 += v0.x + v1.x + v2.x + v3.x;
            q0 += v0.x*v0.x + v1.x*v1.x + v2.x*v2.x + v3.x*v3.x;
            s1 += v0.y + v1.y + v2.y + v3.y;
            q1 += v0.y*v0.y + v1.y*v1.y + v2.y*v2.y + v3.y*v3.y;
            s2 += v0.z + v1.z + v2.z + v3.z;
            q2 += v0.z*v0.z + v1.z*v1.z + v2.z*v2.z + v3.z*v3.z;
            s3 += v0.w + v1.w + v2.w + v3.w;
            q3 += v0.w*v0.w + v1.w*v1.w + v2.w*v2.w + v3.w*v3.w;

            __half2 h;
            unsigned p00, p01, p10, p11, p20, p21, p30, p31;
            h = __floats2half2_rn(v0.x, v1.x); p00 = *(unsigned*)&h;
            h = __floats2half2_rn(v2.x, v3.x); p01 = *(unsigned*)&h;
            h = __floats2half2_rn(v0.y, v1.y); p10 = *(unsigned*)&h;
            h = __floats2half2_rn(v2.y, v3.y); p11 = *(unsigned*)&h;
            h = __floats2half2_rn(v0.z, v1.z); p20 = *(unsigned*)&h;
            h = __floats2half2_rn(v2.z, v3.z); p21 = *(unsigned*)&h;
            h = __floats2half2_rn(v0.w, v1.w); p30 = *(unsigned*)&h;
            h = __floats2half2_rn(v2.w, v3.w); p31 = *(unsigned*)&h;
            const int m = k >> 1;
            if ((k & 1) == 0) {
                out[0][m].x = p00; out[0][m].y = p01;
                out[1][m].x = p10; out[1][m].y = p11;
                out[2][m].x = p20; out[2][m].y = p21;
                out[3][m].x = p30; out[3][m].y = p31;
            } else {
                out[0][m].z = p00; out[0][m].w = p01;
                out[1][m].z = p10; out[1][m].w = p11;
                out[2][m].z = p20; out[2][m].w = p21;
                out[3][m].z = p30; out[3][m].w = p31;
            }
        }
        #pragma unroll
        for (int i = 0; i < 4; ++i) {
            uint4* row = (uint4*)(ln_raw + ((size_t)b * Nn + n0 + t0 + i) * Cc + c0);
            row[0] = out[i][0]; row[1] = out[i][1];
            row[2] = out[i][2]; row[3] = out[i][3];
        }
        ps [cg][t0+0] = s0; ps [cg][t0+1] = s1; ps [cg][t0+2] = s2; ps [cg][t0+3] = s3;
        pss[cg][t0+0] = q0; pss[cg][t0+1] = q1; pss[cg][t0+2] = q2; pss[cg][t0+3] = q3;
    }

    if (tid < nvalid) {
        int bin  = fidx[b * Nn + n0 + tid];
        int cell = b * HWp + bin;
        int slot = atomicAdd(&cntInt[cell], 1);
        if (slot < BUCK) bucket[(size_t)cell * BUCK + slot] = n0 + tid;
    }
    __syncthreads();

    if (tid < nvalid) {
        float sum = 0.f, ssq = 0.f;
        #pragma unroll
        for (int k = 0; k < 8; ++k) { sum += ps[k][tid]; ssq += pss[k][tid]; }
        float mu  = sum * (1.0f / Cc);
        float var = ssq * (1.0f / Cc) - mu * mu;
        mustats[(size_t)b * Nn + n0 + tid] = make_float2(mu, rsqrtf(var + 1e-5f));
    }
}

// ---------------- Kernel 2: per-cell mean + deferred LayerNorm (wave per cell) ----------
__global__ __launch_bounds__(256) void cell_mean_kernel(
    const __half* __restrict__ ln_raw, const float2* __restrict__ mustats,
    const int* __restrict__ cntInt, const int* __restrict__ bucket,
    const float* __restrict__ lnw, const float* __restrict__ lnb,
    __half* __restrict__ grid)
{
    const int wave = (int)((blockIdx.x * 256 + threadIdx.x) >> 6);  // cell index (b*HW+hw)
    const int lane = threadIdx.x & 63;
    const int b    = wave >> 16;

    int cnt = min(cntInt[wave], BUCK);
    float a0 = 0.f, a1 = 0.f, a2 = 0.f, a3 = 0.f;
    for (int t = 0; t < cnt; ++t) {
        int tok = bucket[(size_t)wave * BUCK + t];
        float2 ms = mustats[(size_t)b * Nn + tok];          // wave-uniform broadcast
        uint2 v = ((const uint2*)(ln_raw + ((size_t)b * Nn + tok) * Cc))[lane];
        __half2 p0 = *(__half2*)&v.x, p1 = *(__half2*)&v.y;
        float2 f0 = __half22float2(p0), f1 = __half22float2(p1);
        a0 += (f0.x - ms.x) * ms.y;
        a1 += (f0.y - ms.x) * ms.y;
        a2 += (f1.x - ms.x) * ms.y;
        a3 += (f1.y - ms.x) * ms.y;
    }
    uint2 o;
    if (cnt > 0) {
        const float inv = 1.0f / (float)cnt;
        float4 w4 = *(const float4*)&lnw[lane * 4];
        float4 b4 = *(const float4*)&lnb[lane * 4];
        __half2 o0 = __floats2half2_rn(w4.x * (a0 * inv) + b4.x, w4.y * (a1 * inv) + b4.y);
        __half2 o1 = __floats2half2_rn(w4.z * (a2 * inv) + b4.z, w4.w * (a3 * inv) + b4.w);
        o.x = *(unsigned*)&o0; o.y = *(unsigned*)&o1;
    } else {
        o.x = 0u; o.y = 0u;
    }
    ((uint2*)(grid + (size_t)wave * Cc))[lane] = o;
}

// ---------------- Kernel 3: FUSED depthwise 3x3 -> ReLU -> 3x3 -> scale (R12 form) ------
__global__ __launch_bounds__(256, 2) void dwconv_fused_kernel(
    const __half* __restrict__ in, const float* __restrict__ w1, const float* __restrict__ b1,
    const float* __restrict__ w2, const float* __restrict__ b2,
    const float* __restrict__ sw, __half* __restrict__ out)
{
    __shared__ uint4 in_s [12 * 20 * 8];   // 30.7 KB
    __shared__ uint4 mid_s[10 * 18 * 8];   // 23.0 KB

    const int tid = threadIdx.x;
    const int bid = blockIdx.x;
    const int cgi = bid & 3;
    const int tx  = (bid >> 2) & 15;
    const int ty  = (bid >> 6) & 31;
    const int bo  = bid >> 11;
    const int c0  = cgi * 64;
    const int x0  = tx * 16;
    const int y0  = ty * 8;

    const int u   = tid & 7;
    const int pxl = tid >> 3;

    const __half* gin = in + (size_t)bo * HWp * Cc + c0;
    #pragma unroll
    for (int it = 0; it < 8; ++it) {
        int p = it * 32 + pxl;
        if (p < 240) {
            int r = p / 20, c = p - r * 20;
            int gh = y0 + r - 2, gw = x0 + c - 2;
            uint4 v = make_uint4(0, 0, 0, 0);
            if ((unsigned)gh < 256u && (unsigned)gw < 256u)
                v = *(const uint4*)(gin + ((size_t)(gh * 256 + gw)) * Cc + u * 8);
            in_s[p * 8 + u] = v;
        }
    }

    float wA[72], bA[8];
    {
        const float4* wp = (const float4*)(w1 + (size_t)(c0 + u * 8) * 9);
        #pragma unroll
        for (int i = 0; i < 18; ++i) ((float4*)wA)[i] = wp[i];
        const float4* bp = (const float4*)(b1 + c0 + u * 8);
        ((float4*)bA)[0] = bp[0]; ((float4*)bA)[1] = bp[1];
    }
    __syncthreads();

    #pragma unroll
    for (int it = 0; it < 6; ++it) {
        int p = it * 32 + pxl;             // valid < 180
        if (p < 180) {
            int r = p / 18, c = p - r * 18;
            const int gh = y0 + r - 1, gw = x0 + c - 1;
            const bool inimg = ((unsigned)gh < 256u) && ((unsigned)gw < 256u);
            float acc[8];
            #pragma unroll
            for (int j = 0; j < 8; ++j) acc[j] = bA[j];
            #pragma unroll
            for (int dr = 0; dr < 3; ++dr) {
                #pragma unroll
                for (int dc = 0; dc < 3; ++dc) {
                    uint4 v = in_s[((r + dr) * 20 + (c + dc)) * 8 + u];
                    const int k = dr * 3 + dc;
                    #pragma unroll
                    for (int e = 0; e < 4; ++e) {
                        float2 f = __half22float2(*(const __half2*)&((const unsigned*)&v)[e]);
                        acc[2*e]   += f.x * wA[(2*e)     * 9 + k];
                        acc[2*e+1] += f.y * wA[(2*e + 1) * 9 + k];
                    }
                }
            }
            uint4 o;
            if (inimg) {
                #pragma unroll
                for (int e = 0; e < 4; ++e) {
                    __half2 h = __floats2half2_rn(fmaxf(acc[2*e], 0.f), fmaxf(acc[2*e+1], 0.f));
                    ((unsigned*)&o)[e] = *(unsigned*)&h;
                }
            } else {
                o = make_uint4(0, 0, 0, 0);
            }
            mid_s[p * 8 + u] = o;
        }
    }

    float wB[72], bB[8], sB[8];
    {
        const float4* wp = (const float4*)(w2 + (size_t)(c0 + u * 8) * 9);
        #pragma unroll
        for (int i = 0; i < 18; ++i) ((float4*)wB)[i] = wp[i];
        const float4* bp = (const float4*)(b2 + c0 + u * 8);
        ((float4*)bB)[0] = bp[0]; ((float4*)bB)[1] = bp[1];
        const float4* sp = (const float4*)(sw + c0 + u * 8);
        ((float4*)sB)[0] = sp[0]; ((float4*)sB)[1] = sp[1];
    }
    __syncthreads();

    __half* gout = out + (size_t)bo * HWp * Cc + c0;
    #pragma unroll
    for (int it = 0; it < 4; ++it) {
        int p = it * 32 + pxl;             // 0..127
        int r = p >> 4, c = p & 15;
        float acc[8];
        #pragma unroll
        for (int j = 0; j < 8; ++j) acc[j] = bB[j];
        #pragma unroll
        for (int dr = 0; dr < 3; ++dr) {
            #pragma unroll
            for (int dc = 0; dc < 3; ++dc) {
                uint4 v = mid_s[((r + dr) * 18 + (c + dc)) * 8 + u];
                const int k = dr * 3 + dc;
                #pragma unroll
                for (int e = 0; e < 4; ++e) {
                    float2 f = __half22float2(*(const __half2*)&((const unsigned*)&v)[e]);
                    acc[2*e]   += f.x * wB[(2*e)     * 9 + k];
                    acc[2*e+1] += f.y * wB[(2*e + 1) * 9 + k];
                }
            }
        }
        uint4 o;
        #pragma unroll
        for (int e = 0; e < 4; ++e) {
            __half2 h = __floats2half2_rn(acc[2*e] * sB[2*e], acc[2*e+1] * sB[2*e+1]);
            ((unsigned*)&o)[e] = *(unsigned*)&h;
        }
        int gh = y0 + r, gw = x0 + c;
        *(uint4*)(gout + ((size_t)(gh * 256 + gw)) * Cc + u * 8) = o;
    }
}

// ---------------- Kernel 4: gather + residual (R12 form: no sched_barrier) -------------
__global__ __launch_bounds__(256, 4) void gather_add_kernel(
    const float* __restrict__ tokens, const int* __restrict__ iidx,
    const __half* __restrict__ gcell, float* __restrict__ out)
{
    const int tid = threadIdx.x;
    const int bt  = blockIdx.x;
    const int b   = bt / NB2;
    const int n0  = (bt % NB2) * TOK2;
    const int tq  = tid & 31;
    const int cg  = tid >> 5;
    const int t0  = tq * 4;
    const int c0  = cg * 32;
    const int nvalid = min(TOK2, Nn - n0);   // 128 or 32 -> %4==0

    if (t0 >= nvalid) return;

    const int4 ii = *(const int4*)&iidx[(size_t)b * Nn + n0 + t0];
    const uint4* gb = (const uint4*)(gcell + (size_t)b * HWp * Cc);  // 32 uint4 per cell

    uint4 g0[4], g1[4], g2[4], g3[4];
    const uint4* r0 = gb + (size_t)ii.x * 32 + 4 * cg;
    const uint4* r1 = gb + (size_t)ii.y * 32 + 4 * cg;
    const uint4* r2 = gb + (size_t)ii.z * 32 + 4 * cg;
    const uint4* r3 = gb + (size_t)ii.w * 32 + 4 * cg;
    #pragma unroll
    for (int m = 0; m < 4; ++m) g0[m] = r0[m];
    #pragma unroll
    for (int m = 0; m < 4; ++m) g1[m] = r1[m];
    #pragma unroll
    for (int m = 0; m < 4; ++m) g2[m] = r2[m];
    #pragma unroll
    for (int m = 0; m < 4; ++m) g3[m] = r3[m];

    const float* tb = tokens + (size_t)b * Cc * Nn + n0 + t0;
    float*       ob = out    + (size_t)b * Cc * Nn + n0 + t0;

    #pragma unroll
    for (int m = 0; m < 4; ++m) {
        #pragma unroll
        for (int d = 0; d < 4; ++d) {
            const unsigned u0 = ((const unsigned*)&g0[m])[d];
            const unsigned u1 = ((const unsigned*)&g1[m])[d];
            const unsigned u2 = ((const unsigned*)&g2[m])[d];
            const unsigned u3 = ((const unsigned*)&g3[m])[d];
            const float2 f0 = __half22float2(*(const __half2*)&u0);
            const float2 f1 = __half22float2(*(const __half2*)&u1);
            const float2 f2 = __half22float2(*(const __half2*)&u2);
            const float2 f3 = __half22float2(*(const __half2*)&u3);
            const int cA = c0 + m * 8 + d * 2;
            float4 va = nt_load_f4(&tb[(size_t)cA * Nn]);
            va.x += f0.x; va.y += f1.x; va.z += f2.x; va.w += f3.x;
            nt_store_f4(va, &ob[(size_t)cA * Nn]);
            float4 vb = nt_load_f4(&tb[(size_t)(cA + 1) * Nn]);
            vb.x += f0.y; vb.y += f1.y; vb.z += f2.y; vb.w += f3.y;
            nt_store_f4(vb, &ob[(size_t)(cA + 1) * Nn]);
        }
    }
}

extern "C" void kernel_launch(void* const* d_in, const int* in_sizes, int n_in,
                              void* d_out, int out_size, void* d_ws, size_t ws_size,
                              hipStream_t stream)
{
    const float* tokens      = (const float*)d_in[0];
    const int*   flatten_idx = (const int*)  d_in[1];
    const int*   inflate_idx = (const int*)  d_in[2];
    const float* lnw         = (const float*)d_in[3];
    const float* lnb         = (const float*)d_in[4];
    const float* w1          = (const float*)d_in[5];
    const float* b1          = (const float*)d_in[6];
    const float* w2          = (const float*)d_in[7];
    const float* b2          = (const float*)d_in[8];
    const float* sw          = (const float*)d_in[9];
    float*       out         = (float*)d_out;

    char* ws = (char*)d_ws;
    const size_t gridBytes = (size_t)Bb * HWp * Cc * sizeof(__half);   // 33.6 MB each
    const size_t lnBytes   = (size_t)Bb * Nn * Cc * sizeof(__half);    // 102.4 MB
    const size_t msBytes   = (size_t)Bb * Nn * sizeof(float2);         // 1.6 MB
    __half* grid    = (__half*)ws;
    __half* grid2   = (__half*)(ws + gridBytes);
    __half* ln_raw  = (__half*)(ws + 2 * gridBytes);
    float2* mustats = (float2*)(ws + 2 * gridBytes + lnBytes);
    int*    cntInt  = (int*)   (ws + 2 * gridBytes + lnBytes + msBytes);
    int*    bucket  = (int*)   (ws + 2 * gridBytes + lnBytes + msBytes + (size_t)Bb * HWp * sizeof(int));

    zero_cnt_kernel<<<(Bb * HWp * sizeof(int)) / (256 * 16), 256, 0, stream>>>((uint4*)cntInt);
    ln_bucket_kernel<<<Bb * NB2, 256, 0, stream>>>(tokens, flatten_idx,
                                                   ln_raw, mustats, cntInt, bucket);
    cell_mean_kernel<<<(Bb * HWp) / 4, 256, 0, stream>>>(ln_raw, mustats, cntInt, bucket,
                                                         lnw, lnb, grid);
    dwconv_fused_kernel<<<4096, 256, 0, stream>>>(grid, w1, b1, w2, b2, sw, grid2);
    gather_add_kernel<<<Bb * NB2, 256, 0, stream>>>(tokens, inflate_idx, grid2, out);
}